// Round 7
// baseline (570.544 us; speedup 1.0000x reference)
//
#include <hip/hip_runtime.h>
#include <hip/hip_bf16.h>
#include <hip/hip_cooperative_groups.h>

namespace cg = cooperative_groups;

typedef short bf16x8 __attribute__((ext_vector_type(8)));
typedef float f32x4 __attribute__((ext_vector_type(4)));

#define BSH 7            // 128 targets per bucket
#define BK  (1 << BSH)

static inline int cdiv(int a, int b){ return (a + b - 1) / b; }

__device__ __forceinline__ unsigned pack_bf16_hi(float v){
    return ((unsigned)__bfloat16_as_ushort(__float2bfloat16(v))) << 16;
}
__device__ __forceinline__ float bf16hi_to_f32(unsigned bits_hi16){
    return __uint_as_float(bits_hi16);  // bf16 bits already in [31:16]
}

// =================== fused prep: ONE cooperative launch ========================
// phases (grid.sync between): 0 zero gcnt | 1 bucket histogram | 2 scan (blk 0)
// | 3 bin edges | 4 per-bucket CSR finalize + deg/dinv | 5 normv + xg + BT.
// Phase bodies == the proven round-6 kernels verbatim. 12KB LDS, <=391 blocks.
__global__ __launch_bounds__(256) void k_coprep(
        const int* __restrict__ src, const int* __restrict__ tgt,
        const float* __restrict__ asp, const float* __restrict__ actx,
        const float* __restrict__ alat, const float* __restrict__ wsp,
        const float* __restrict__ wctx, const float* __restrict__ wlat,
        const float* __restrict__ dp, const float* __restrict__ x,
        const float* __restrict__ Wself, const float* __restrict__ W3,
        int* __restrict__ gcnt, int* __restrict__ bbase, int* __restrict__ gcur,
        int* __restrict__ rs, uint2* __restrict__ effo, uint2* __restrict__ nv,
        float* __restrict__ dinv_all, __hip_bfloat16* __restrict__ xg,
        __hip_bfloat16* __restrict__ BT,
        int N, int E, int L, int NB){
    cg::grid_group grid = cg::this_grid();
    __shared__ int sm0[1024], sm1[1024], sm2[1024];
    const int tid = threadIdx.x, bid = blockIdx.x, nblk = gridDim.x;
    const int nch = (E + 4095) >> 12;
    uint4* binned = (uint4*)nv;   // binned dead before nv written (phase 5)

    // ---- phase 0: zero gcnt ----
    if (bid == 0) for (int b = tid; b < 1024; b += 256) gcnt[b] = 0;
    grid.sync();

    // ---- phase 1: bucket histogram ----
    for (int ch = bid; ch < nch; ch += nblk){
        for (int b = tid; b < 1024; b += 256) sm0[b] = 0;
        __syncthreads();
        int c0 = ch << 12;
        #pragma unroll
        for (int u = 0; u < 16; ++u){
            int e = c0 + u * 256 + tid;
            if (e < E) atomicAdd(&sm0[tgt[e] >> BSH], 1);
        }
        __syncthreads();
        for (int b = tid; b < NB; b += 256){
            int c = sm0[b];
            if (c) atomicAdd(&gcnt[b], c);
        }
        __syncthreads();
    }
    grid.sync();

    // ---- phase 2: scan bucket counts -> bases (block 0) ----
    if (bid == 0){
        int b0 = tid * 4;
        int v0 = gcnt[b0], v1 = gcnt[b0 + 1], v2 = gcnt[b0 + 2], v3 = gcnt[b0 + 3];
        int t3 = v0 + v1 + v2 + v3;
        sm0[tid] = t3;
        __syncthreads();
        for (int off = 1; off < 256; off <<= 1){
            int xx = (tid >= off) ? sm0[tid - off] : 0;
            __syncthreads();
            sm0[tid] += xx;
            __syncthreads();
        }
        int ex = sm0[tid] - t3;
        bbase[b0]     = ex;
        bbase[b0 + 1] = ex + v0;
        bbase[b0 + 2] = ex + v0 + v1;
        bbase[b0 + 3] = ex + v0 + v1 + v2;
        gcur[b0] = bbase[b0]; gcur[b0 + 1] = bbase[b0 + 1];
        gcur[b0 + 2] = bbase[b0 + 2]; gcur[b0 + 3] = bbase[b0 + 3];
        if (tid == 255) bbase[1024] = sm0[255];   // == E
        if (tid == 0)   rs[N] = E;
    }
    grid.sync();

    // ---- phase 3: bin edges into bucket-contiguous regions ----
    for (int ch = bid; ch < nch; ch += nblk){
        int* lh = sm0; int* lc = sm1; int* gb = sm2;
        for (int b = tid; b < 1024; b += 256){ lh[b] = 0; lc[b] = 0; }
        __syncthreads();
        int c0 = ch << 12;
        #pragma unroll
        for (int u = 0; u < 16; ++u){
            int e = c0 + u * 256 + tid;
            if (e < E) atomicAdd(&lh[tgt[e] >> BSH], 1);
        }
        __syncthreads();
        for (int b = tid; b < NB; b += 256){
            int c = lh[b];
            gb[b] = c ? atomicAdd(&gcur[b], c) : 0;
        }
        __syncthreads();
        #pragma unroll
        for (int u = 0; u < 16; ++u){
            int e = c0 + u * 256 + tid;
            if (e < E){
                int t = tgt[e];
                int b = t >> BSH;
                int p = gb[b] + atomicAdd(&lc[b], 1);
                uint4 o;
                o.x = (unsigned)src[e] | pack_bf16_hi(asp[e] * wsp[e]);
                o.y = (pack_bf16_hi(actx[e] * wctx[e]) >> 16) | pack_bf16_hi(alat[e] * wlat[e]);
                o.z = (unsigned)t;
                o.w = 0u;
                binned[p] = o;
            }
        }
        __syncthreads();
    }
    grid.sync();

    // ---- phase 4: per-bucket CSR finalize + deg/dinv for all layers ----
    for (int b = bid; b < NB; b += nblk){
        int* th  = sm0;        // [128]
        int* sc2 = sm0 + 128;  // [128]
        int* cur = sm0 + 256;  // [128]
        float* smf = (float*)sm1;  // [384]
        int t0 = b << BSH;
        int ebeg = bbase[b], eend = bbase[b + 1];
        if (tid < 128) th[tid] = 0;
        for (int j = tid; j < 384; j += 256) smf[j] = 0.f;
        __syncthreads();
        for (int i = ebeg + tid; i < eend; i += 256)
            atomicAdd(&th[(int)binned[i].z - t0], 1);
        __syncthreads();
        int v = (tid < 128) ? th[tid] : 0;
        if (tid < 128) sc2[tid] = v;
        __syncthreads();
        for (int off = 1; off < 128; off <<= 1){
            int xx = (tid >= off && tid < 128) ? sc2[tid - off] : 0;
            __syncthreads();
            if (tid < 128) sc2[tid] += xx;
            __syncthreads();
        }
        if (tid < 128){
            int exv = sc2[tid] - v;
            cur[tid] = exv;
            int t = t0 + tid;
            if (t < N) rs[t] = ebeg + exv;
        }
        __syncthreads();
        for (int i = ebeg + tid; i < eend; i += 256){
            uint4 r = binned[i];
            int loc = (int)r.z - t0;
            int p = atomicAdd(&cur[loc], 1);
            uint2 o = {r.x, r.y};
            effo[ebeg + p] = o;
            atomicAdd(&smf[loc * 3 + 0], bf16hi_to_f32(r.x & 0xFFFF0000u));
            atomicAdd(&smf[loc * 3 + 1], bf16hi_to_f32(r.y << 16));
            atomicAdd(&smf[loc * 3 + 2], bf16hi_to_f32(r.y & 0xFFFF0000u));
        }
        __syncthreads();
        if (tid < 128){
            int t = t0 + tid;
            if (t < N){
                float d0 = fmaxf(1.f + smf[tid * 3 + 0], 1e-6f);
                float d1 = fmaxf(1.f + smf[tid * 3 + 1], 1e-6f);
                float d2 = fmaxf(1.f + smf[tid * 3 + 2], 1e-6f);
                for (int l = 0; l < L; ++l){
                    size_t base = ((size_t)l * N + t) * 3;
                    dinv_all[base + 0] = powf(d0, dp[l * 3 + 0]);
                    dinv_all[base + 1] = powf(d1, dp[l * 3 + 1]);
                    dinv_all[base + 2] = powf(d2, dp[l * 3 + 2]);
                }
            }
        }
        __syncthreads();
    }
    grid.sync();

    // ---- phase 5: nv (all layers) + xg convert (float4) + BT concat ----
    {
        const int gstride = nblk * 256;
        const int gidx = bid * 256 + tid;
        // nv[l*E+e] = {src, eff_c * dinv_c[l][src]}  (binned now dead)
        for (int i = gidx; i < L * E; i += gstride){
            int l = i / E;
            int e = i - l * E;
            const float* dinv = dinv_all + (size_t)l * N * 3;
            uint2 vv = effo[e];
            unsigned s = vv.x & 0xFFFFu;
            float e0 = bf16hi_to_f32(vv.x & 0xFFFF0000u);
            float e1 = bf16hi_to_f32(vv.y << 16);
            float e2 = bf16hi_to_f32(vv.y & 0xFFFF0000u);
            uint2 o;
            o.x = s | pack_bf16_hi(e0 * dinv[3 * s + 0]);
            o.y = (pack_bf16_hi(e1 * dinv[3 * s + 1]) >> 16)
                | pack_bf16_hi(e2 * dinv[3 * s + 2]);
            nv[i] = o;
        }
        // xg: fp32 -> bf16, 4 at a time
        int nx4 = (N * 128) >> 2;
        for (int i = gidx; i < nx4; i += gstride){
            float4 v = ((const float4*)x)[i];
            float2 lo = {v.x, v.y}, hi = {v.z, v.w};
            ((__hip_bfloat162*)xg)[2 * i]     = __float22bfloat162_rn(lo);
            ((__hip_bfloat162*)xg)[2 * i + 1] = __float22bfloat162_rn(hi);
        }
        // BT concat
        int nw = L * 65536;
        for (int q = gidx; q < nw; q += gstride){
            int l = q >> 16, r = q & 65535;
            int j = r >> 9, k = r & 511;
            float v;
            if (k < 128) v = Wself[l * 16384 + k * 128 + j];
            else {
                int c = (k >> 7) - 1, kk = k & 127;
                v = W3[l * 49152 + (c * 128 + kk) * 128 + j];
            }
            BT[q] = __float2bfloat16(v);
        }
    }
}

// ---------------- aggregate: Y_c[t] = dt_c * sum_e nv_c[e] * x[src[e]] ----------
// round-0 proven structure (wave/target, 2 cols/lane, unroll-8, 28 VGPR, 62% occ).
// Confirmed at its floor: FETCH 100.6MB compulsory, ~2.9 TB/s effective.
__global__ __launch_bounds__(256) void k_msg(
        const __hip_bfloat16* __restrict__ xg,  // [N][128] bf16 compact
        __hip_bfloat16* __restrict__ Yg,        // [N][384] bf16 compact (out)
        const uint2* __restrict__ nv,           // [E] packed, CSR order (this layer)
        const int* __restrict__ rs,             // [N+1]
        const float* __restrict__ dinv,         // [N][3] (this layer)
        int N){
    int w = threadIdx.x >> 6, lane = threadIdx.x & 63;
    int t = blockIdx.x * 4 + w;
    if (t >= N) return;
    float ax0 = 0.f, ay0 = 0.f, ax1 = 0.f, ay1 = 0.f, ax2 = 0.f, ay2 = 0.f;
    int beg = rs[t], end = rs[t + 1];
    int i = beg;
    for (; i + 8 <= end; i += 8){
        uint2 m[8];
        #pragma unroll
        for (int u = 0; u < 8; ++u) m[u] = nv[i + u];
        float2 f[8];
        #pragma unroll
        for (int u = 0; u < 8; ++u){
            const __hip_bfloat162* p =
                (const __hip_bfloat162*)(xg + (size_t)(m[u].x & 0xFFFFu) * 128);
            f[u] = __bfloat1622float2(p[lane]);
        }
        #pragma unroll
        for (int u = 0; u < 8; ++u){
            float n0 = bf16hi_to_f32(m[u].x & 0xFFFF0000u);
            float n1 = bf16hi_to_f32(m[u].y << 16);
            float n2 = bf16hi_to_f32(m[u].y & 0xFFFF0000u);
            ax0 += n0 * f[u].x; ay0 += n0 * f[u].y;
            ax1 += n1 * f[u].x; ay1 += n1 * f[u].y;
            ax2 += n2 * f[u].x; ay2 += n2 * f[u].y;
        }
    }
    for (; i < end; ++i){
        uint2 m = nv[i];
        const __hip_bfloat162* p =
            (const __hip_bfloat162*)(xg + (size_t)(m.x & 0xFFFFu) * 128);
        float2 fv = __bfloat1622float2(p[lane]);
        float n0 = bf16hi_to_f32(m.x & 0xFFFF0000u);
        float n1 = bf16hi_to_f32(m.y << 16);
        float n2 = bf16hi_to_f32(m.y & 0xFFFF0000u);
        ax0 += n0 * fv.x; ay0 += n0 * fv.y;
        ax1 += n1 * fv.x; ay1 += n1 * fv.y;
        ax2 += n2 * fv.x; ay2 += n2 * fv.y;
    }
    float dt0 = dinv[3 * t], dt1 = dinv[3 * t + 1], dt2 = dinv[3 * t + 2];
    __hip_bfloat162* yo = (__hip_bfloat162*)(Yg + (size_t)t * 384) + lane;
    float2 r0 = {dt0 * ax0, dt0 * ay0};
    float2 r1 = {dt1 * ax1, dt1 * ay1};
    float2 r2 = {dt2 * ax2, dt2 * ay2};
    yo[0]   = __float22bfloat162_rn(r0);
    yo[64]  = __float22bfloat162_rn(r1);
    yo[128] = __float22bfloat162_rn(r2);
}

// ---------------- GEMM: out = [xg|Yg][M,512] @ B[512,128] + bias; opt fused LN+ReLU
__global__ __launch_bounds__(256) void k_gemm(
        const __hip_bfloat16* __restrict__ Yg,  // [M,384] bf16
        const __hip_bfloat16* __restrict__ BT,  // [128,512] bf16 ([j][k])
        const float* __restrict__ bias,         // [128] fp32
        float* __restrict__ outbuf,             // [M,128] (doLN==0)
        int M, int doLN,
        const float* __restrict__ g, const float* __restrict__ b,
        __hip_bfloat16* __restrict__ xg){       // [M,128]: A kt=0 source; LN target
    __shared__ __hip_bfloat16 As[128 * 128];
    __shared__ __hip_bfloat16 Bs[128 * 128];
    const int tid = threadIdx.x;
    const int row0 = blockIdx.x * 128;
    const int w = tid >> 6, lane = tid & 63;
    const int wm = (w & 1) * 64, wn = (w >> 1) * 64;
    const int lm = lane & 15, lq = lane >> 4;

    f32x4 acc[4][4];
    #pragma unroll
    for (int mt = 0; mt < 4; ++mt)
        #pragma unroll
        for (int nt = 0; nt < 4; ++nt)
            acc[mt][nt] = {0.f, 0.f, 0.f, 0.f};

    for (int kt = 0; kt < 4; ++kt){
        #pragma unroll
        for (int it = 0; it < 8; ++it){
            int v = it * 256 + tid;
            int r = v >> 4, c = v & 15;
            int soff = r * 128 + ((c ^ (r & 15)) << 3);
            int4 av = {0, 0, 0, 0};
            if (row0 + r < M){
                if (kt == 0)
                    av = *(const int4*)(xg + (size_t)(row0 + r) * 128 + (c << 3));
                else
                    av = *(const int4*)(Yg + (size_t)(row0 + r) * 384
                                        + (kt - 1) * 128 + (c << 3));
            }
            *(int4*)(&As[soff]) = av;
            int4 bv = *(const int4*)(BT + (size_t)r * 512 + kt * 128 + (c << 3));
            *(int4*)(&Bs[soff]) = bv;
        }
        __syncthreads();

        #pragma unroll
        for (int kk = 0; kk < 4; ++kk){
            int kc = kk * 4 + lq;
            bf16x8 a[4], b2[4];
            #pragma unroll
            for (int mt = 0; mt < 4; ++mt){
                int r = wm + mt * 16 + lm;
                a[mt] = *(const bf16x8*)(&As[r * 128 + ((kc ^ (r & 15)) << 3)]);
            }
            #pragma unroll
            for (int nt = 0; nt < 4; ++nt){
                int r = wn + nt * 16 + lm;
                b2[nt] = *(const bf16x8*)(&Bs[r * 128 + ((kc ^ (r & 15)) << 3)]);
            }
            #pragma unroll
            for (int mt = 0; mt < 4; ++mt)
                #pragma unroll
                for (int nt = 0; nt < 4; ++nt)
                    acc[mt][nt] = __builtin_amdgcn_mfma_f32_16x16x32_bf16(
                        a[mt], b2[nt], acc[mt][nt], 0, 0, 0);
        }
        __syncthreads();
    }

    if (!doLN){
        #pragma unroll
        for (int mt = 0; mt < 4; ++mt){
            #pragma unroll
            for (int nt = 0; nt < 4; ++nt){
                int col = wn + nt * 16 + lm;
                #pragma unroll
                for (int r = 0; r < 4; ++r){
                    int row = row0 + wm + mt * 16 + lq * 4 + r;
                    if (row < M)
                        outbuf[(size_t)row * 128 + col] = acc[mt][nt][r] + bias[col];
                }
            }
        }
    } else {
        float* S1 = (float*)As;          // [128][32] sum partials
        float* S2 = S1 + 4096;           // [128][32] sumsq partials
        float* MS = (float*)Bs;          // mu[128], sc[128]
        const int half = wn >> 6;        // 0 or 1
        const int slot = half * 16 + lm;
        float bv[4];
        #pragma unroll
        for (int nt = 0; nt < 4; ++nt) bv[nt] = bias[wn + nt * 16 + lm];
        #pragma unroll
        for (int mt = 0; mt < 4; ++mt){
            #pragma unroll
            for (int r = 0; r < 4; ++r){
                int rl = wm + mt * 16 + lq * 4 + r;
                float ps = 0.f, pq = 0.f;
                #pragma unroll
                for (int nt = 0; nt < 4; ++nt){
                    float v = acc[mt][nt][r] + bv[nt];
                    ps += v; pq += v * v;
                }
                S1[rl * 32 + slot] = ps;
                S2[rl * 32 + slot] = pq;
            }
        }
        __syncthreads();
        if (tid < 128){
            float s = 0.f, sq = 0.f;
            #pragma unroll
            for (int j = 0; j < 32; ++j){
                s  += S1[tid * 32 + j];
                sq += S2[tid * 32 + j];
            }
            float mu = s * (1.0f / 128.0f);
            float var = sq * (1.0f / 128.0f) - mu * mu;
            MS[tid] = mu;
            MS[128 + tid] = rsqrtf(var + 1e-5f);
        }
        __syncthreads();
        float gv[4], bbv[4];
        #pragma unroll
        for (int nt = 0; nt < 4; ++nt){
            int col = wn + nt * 16 + lm;
            gv[nt] = g[col]; bbv[nt] = b[col];
        }
        #pragma unroll
        for (int mt = 0; mt < 4; ++mt){
            #pragma unroll
            for (int r = 0; r < 4; ++r){
                int rl = wm + mt * 16 + lq * 4 + r;
                int row = row0 + rl;
                if (row < M){
                    float mu = MS[rl], sc = MS[128 + rl];
                    #pragma unroll
                    for (int nt = 0; nt < 4; ++nt){
                        int col = wn + nt * 16 + lm;
                        float v = acc[mt][nt][r] + bv[nt];
                        float y = fmaxf((v - mu) * sc * gv[nt] + bbv[nt], 0.0f);
                        xg[(size_t)row * 128 + col] = __float2bfloat16(y);
                    }
                }
            }
        }
    }
}

extern "C" void kernel_launch(void* const* d_in, const int* in_sizes, int n_in,
                              void* d_out, int out_size, void* d_ws, size_t ws_size,
                              hipStream_t stream) {
    const float* x     = (const float*)d_in[0];
    const int*   ei    = (const int*)d_in[1];
    const float* asp   = (const float*)d_in[2];
    const float* actx  = (const float*)d_in[3];
    const float* alat  = (const float*)d_in[4];
    const float* wsp   = (const float*)d_in[5];
    const float* wctx  = (const float*)d_in[6];
    const float* wlat  = (const float*)d_in[7];
    const float* W3    = (const float*)d_in[8];
    const float* Wself = (const float*)d_in[9];
    const float* bias  = (const float*)d_in[10];
    const float* dpow  = (const float*)d_in[11];
    const float* lng   = (const float*)d_in[12];
    const float* lnb   = (const float*)d_in[13];

    int N = in_sizes[0] / 128;
    int E = in_sizes[1] / 2;
    int L = in_sizes[8] / (3 * 128 * 128);
    int NB = cdiv(N, BK);
    const int* src = ei;
    const int* tgt = ei + E;

    // workspace carve (256B-aligned) — layout identical to round 6 (passed)
    char* p = (char*)d_ws;
    auto alloc = [&](size_t bytes) -> void* {
        void* r = (void*)p;
        p += (bytes + 255) & ~(size_t)255;
        return r;
    };
    int*   rs       = (int*)  alloc((size_t)(N + 1) * 4);
    int*   gcnt     = (int*)  alloc(1024 * 4);
    int*   bbase    = (int*)  alloc(1025 * 4);
    int*   gcur     = (int*)  alloc(1024 * 4);
    uint2* effo     = (uint2*)alloc((size_t)E * 8);
    size_t nv_bytes = (size_t)L * E * 8, bn_bytes = (size_t)E * 16;
    uint2* nv       = (uint2*)alloc(nv_bytes > bn_bytes ? nv_bytes : bn_bytes);
    float* dinv_all = (float*)alloc((size_t)L * N * 3 * 4);   // [L][N][3]
    __hip_bfloat16* xg = (__hip_bfloat16*)alloc((size_t)N * 128 * 2);  // [N][128]
    __hip_bfloat16* Yg = (__hip_bfloat16*)alloc((size_t)N * 384 * 2);  // [N][384]
    __hip_bfloat16* BT = (__hip_bfloat16*)alloc((size_t)L * 128 * 512 * 2);

    // ---- prep: single cooperative launch (was 7 dispatches) ----
    {
        int nch = cdiv(E, 4096);
        int gblocks = NB > nch ? NB : nch;     // 391 for N=50k/E=1M; co-resident OK
        void* kargs[] = {
            (void*)&src, (void*)&tgt, (void*)&asp, (void*)&actx, (void*)&alat,
            (void*)&wsp, (void*)&wctx, (void*)&wlat, (void*)&dpow, (void*)&x,
            (void*)&Wself, (void*)&W3, (void*)&gcnt, (void*)&bbase, (void*)&gcur,
            (void*)&rs, (void*)&effo, (void*)&nv, (void*)&dinv_all, (void*)&xg,
            (void*)&BT, (void*)&N, (void*)&E, (void*)&L, (void*)&NB };
        hipLaunchCooperativeKernel((void*)k_coprep, dim3(gblocks), dim3(256),
                                   kargs, 0, stream);
    }

    // ---- layers ----
    for (int l = 0; l < L; ++l){
        int doLN = (l < L - 1) ? 1 : 0;
        const float* dinv_l = dinv_all + (size_t)l * N * 3;
        k_msg <<<cdiv(N, 4), 256, 0, stream>>>(xg, Yg, nv + (size_t)l * E, rs, dinv_l, N);
        k_gemm<<<cdiv(N, 128), 256, 0, stream>>>(Yg, BT + (size_t)l * 65536,
                                                 bias + l * 128, (float*)d_out, N,
                                                 doLN, lng, lnb, xg);
    }
}

// Round 8
// 351.303 us; speedup vs baseline: 1.6241x; 1.6241x over previous
//
#include <hip/hip_runtime.h>
#include <hip/hip_bf16.h>

typedef short bf16x8 __attribute__((ext_vector_type(8)));
typedef float f32x4 __attribute__((ext_vector_type(4)));

#define BSH 7            // 128 targets per bucket
#define BK  (1 << BSH)

static inline int cdiv(int a, int b){ return (a + b - 1) / b; }

__device__ __forceinline__ unsigned pack_bf16_hi(float v){
    return ((unsigned)__bfloat16_as_ushort(__float2bfloat16(v))) << 16;
}
__device__ __forceinline__ float bf16hi_to_f32(unsigned bits_hi16){
    return __uint_as_float(bits_hi16);  // bf16 bits already in [31:16]
}

// ---------- pass 0: global bucket histogram (LDS-privatized) ----------
__global__ __launch_bounds__(256) void k_bcnt0(const int* __restrict__ tgt,
                                               int* __restrict__ gcnt, int E, int NB){
    __shared__ int lh[1024];
    int tid = threadIdx.x;
    for (int b = tid; b < 1024; b += 256) lh[b] = 0;
    __syncthreads();
    int c0 = blockIdx.x * 4096;
    #pragma unroll
    for (int u = 0; u < 16; ++u){
        int e = c0 + u * 256 + tid;
        if (e < E) atomicAdd(&lh[tgt[e] >> BSH], 1);
    }
    __syncthreads();
    for (int b = tid; b < NB; b += 256){
        int c = lh[b];
        if (c) atomicAdd(&gcnt[b], c);
    }
}

// ---------- pass 0.5: scan bucket counts -> bases (= CSR bucket bases) ----------
__global__ __launch_bounds__(256) void k_bscan(const int* __restrict__ gcnt,
                                               int* __restrict__ bbase,
                                               int* __restrict__ gcur,
                                               int* __restrict__ rs,
                                               int N, int E){
    __shared__ int sc[256];
    int tid = threadIdx.x;
    int b0 = tid * 4;
    int v0 = gcnt[b0], v1 = gcnt[b0 + 1], v2 = gcnt[b0 + 2], v3 = gcnt[b0 + 3];
    int t3 = v0 + v1 + v2 + v3;
    sc[tid] = t3;
    __syncthreads();
    for (int off = 1; off < 256; off <<= 1){
        int x = (tid >= off) ? sc[tid - off] : 0;
        __syncthreads();
        sc[tid] += x;
        __syncthreads();
    }
    int ex = sc[tid] - t3;
    bbase[b0]     = ex;
    bbase[b0 + 1] = ex + v0;
    bbase[b0 + 2] = ex + v0 + v1;
    bbase[b0 + 3] = ex + v0 + v1 + v2;
    gcur[b0] = bbase[b0]; gcur[b0 + 1] = bbase[b0 + 1];
    gcur[b0 + 2] = bbase[b0 + 2]; gcur[b0 + 3] = bbase[b0 + 3];
    if (tid == 255) bbase[1024] = sc[255];   // == E
    if (tid == 0)   rs[N] = E;
}

// ---------- pass 1: bin edges into bucket-contiguous regions (direct write) ----------
__global__ __launch_bounds__(256) void k_bin(
        const int* __restrict__ src, const int* __restrict__ tgt,
        const float* __restrict__ asp, const float* __restrict__ actx,
        const float* __restrict__ alat, const float* __restrict__ wsp,
        const float* __restrict__ wctx, const float* __restrict__ wlat,
        int* __restrict__ gcur, uint4* __restrict__ binned, int E, int NB){
    __shared__ int lh[1024], lc[1024], gb[1024];
    int tid = threadIdx.x;
    int c0 = blockIdx.x * 4096;
    for (int b = tid; b < 1024; b += 256){ lh[b] = 0; lc[b] = 0; }
    __syncthreads();
    #pragma unroll
    for (int u = 0; u < 16; ++u){
        int e = c0 + u * 256 + tid;
        if (e < E) atomicAdd(&lh[tgt[e] >> BSH], 1);
    }
    __syncthreads();
    for (int b = tid; b < NB; b += 256){
        int c = lh[b];
        gb[b] = c ? atomicAdd(&gcur[b], c) : 0;
    }
    __syncthreads();
    #pragma unroll
    for (int u = 0; u < 16; ++u){
        int e = c0 + u * 256 + tid;
        if (e < E){
            int t = tgt[e];
            int b = t >> BSH;
            int p = gb[b] + atomicAdd(&lc[b], 1);
            uint4 o;
            o.x = (unsigned)src[e] | pack_bf16_hi(asp[e] * wsp[e]);
            o.y = (pack_bf16_hi(actx[e] * wctx[e]) >> 16) | pack_bf16_hi(alat[e] * wlat[e]);
            o.z = (unsigned)t;
            o.w = 0u;
            binned[p] = o;
        }
    }
}

// ---------- pass 2: per-bucket CSR finalize (writes rs + final effo)
//            + fused per-target deg sums -> dinv_all for ALL layers ----------
__global__ __launch_bounds__(256) void k_bucket(
        const uint4* __restrict__ binned, const int* __restrict__ bbase,
        const float* __restrict__ dp,        // [L*3]
        uint2* __restrict__ effo, int* __restrict__ rs,
        float* __restrict__ dinv_all,        // [L][N][3]
        int N, int L){
    __shared__ int th[128], sc2[128], cur[128];
    __shared__ float sm[384];
    int tid = threadIdx.x;
    int b = blockIdx.x;
    int t0 = b << BSH;
    int ebeg = bbase[b], eend = bbase[b + 1];
    if (tid < 128) th[tid] = 0;
    for (int j = tid; j < 384; j += 256) sm[j] = 0.f;
    __syncthreads();
    for (int i = ebeg + tid; i < eend; i += 256)
        atomicAdd(&th[(int)binned[i].z - t0], 1);
    __syncthreads();
    int v = (tid < 128) ? th[tid] : 0;
    if (tid < 128) sc2[tid] = v;
    __syncthreads();
    for (int off = 1; off < 128; off <<= 1){
        int x = (tid >= off && tid < 128) ? sc2[tid - off] : 0;
        __syncthreads();
        if (tid < 128) sc2[tid] += x;
        __syncthreads();
    }
    if (tid < 128){
        int exv = sc2[tid] - v;
        cur[tid] = exv;
        int t = t0 + tid;
        if (t < N) rs[t] = ebeg + exv;
    }
    __syncthreads();
    for (int i = ebeg + tid; i < eend; i += 256){
        uint4 r = binned[i];
        int loc = (int)r.z - t0;
        int p = atomicAdd(&cur[loc], 1);
        uint2 o = {r.x, r.y};
        effo[ebeg + p] = o;
        atomicAdd(&sm[loc * 3 + 0], bf16hi_to_f32(r.x & 0xFFFF0000u));
        atomicAdd(&sm[loc * 3 + 1], bf16hi_to_f32(r.y << 16));
        atomicAdd(&sm[loc * 3 + 2], bf16hi_to_f32(r.y & 0xFFFF0000u));
    }
    __syncthreads();
    if (tid < 128){
        int t = t0 + tid;
        if (t < N){
            float d0 = fmaxf(1.f + sm[tid * 3 + 0], 1e-6f);
            float d1 = fmaxf(1.f + sm[tid * 3 + 1], 1e-6f);
            float d2 = fmaxf(1.f + sm[tid * 3 + 2], 1e-6f);
            for (int l = 0; l < L; ++l){
                size_t base = ((size_t)l * N + t) * 3;
                dinv_all[base + 0] = powf(d0, dp[l * 3 + 0]);
                dinv_all[base + 1] = powf(d1, dp[l * 3 + 1]);
                dinv_all[base + 2] = powf(d2, dp[l * 3 + 2]);
            }
        }
    }
}

// -------- merged prep: nv (all layers) + xg convert (float4) + BT concat -------
// Full-size grid (unlike the failed cooperative version) — one launch, 3 ranges.
__global__ void k_prep(const uint2* __restrict__ effo,
                       const float* __restrict__ dinv_all,  // [L][N][3]
                       uint2* __restrict__ nv,
                       const float* __restrict__ x, __hip_bfloat16* __restrict__ xg,
                       const float* __restrict__ Wself, const float* __restrict__ W3,
                       __hip_bfloat16* __restrict__ BT,
                       int N, int E, int L){
    int gid = blockIdx.x * 256 + threadIdx.x;
    int LE = L * E;
    int nx4 = (N * 128) >> 2;
    int nw = L * 65536;
    if (gid < LE){
        int l = gid / E;
        int e = gid - l * E;
        const float* dinv = dinv_all + (size_t)l * N * 3;
        uint2 v = effo[e];
        unsigned s = v.x & 0xFFFFu;
        float e0 = bf16hi_to_f32(v.x & 0xFFFF0000u);
        float e1 = bf16hi_to_f32(v.y << 16);
        float e2 = bf16hi_to_f32(v.y & 0xFFFF0000u);
        uint2 o;
        o.x = s | pack_bf16_hi(e0 * dinv[3 * s + 0]);
        o.y = (pack_bf16_hi(e1 * dinv[3 * s + 1]) >> 16)
            | pack_bf16_hi(e2 * dinv[3 * s + 2]);
        nv[gid] = o;
    } else if (gid < LE + nx4){
        int i = gid - LE;
        float4 v = ((const float4*)x)[i];
        float2 lo = {v.x, v.y}, hi = {v.z, v.w};
        ((__hip_bfloat162*)xg)[2 * i]     = __float22bfloat162_rn(lo);
        ((__hip_bfloat162*)xg)[2 * i + 1] = __float22bfloat162_rn(hi);
    } else if (gid < LE + nx4 + nw){
        int q = gid - LE - nx4;
        int l = q >> 16, r = q & 65535;
        int j = r >> 9, k = r & 511;
        float v;
        if (k < 128) v = Wself[l * 16384 + k * 128 + j];
        else {
            int c = (k >> 7) - 1, kk = k & 127;
            v = W3[l * 49152 + (c * 128 + kk) * 128 + j];
        }
        BT[q] = __float2bfloat16(v);
    }
}

// ---------------- aggregate: Y_c[t] = dt_c * sum_e nv_c[e] * x[src[e]] ----------
// round-0 proven structure — AT ITS FLOOR (48.2us, 100.6MB compulsory, 2.9TB/s).
__global__ __launch_bounds__(256) void k_msg(
        const __hip_bfloat16* __restrict__ xg,  // [N][128] bf16 compact
        __hip_bfloat16* __restrict__ Yg,        // [N][384] bf16 compact (out)
        const uint2* __restrict__ nv,           // [E] packed, CSR order (this layer)
        const int* __restrict__ rs,             // [N+1]
        const float* __restrict__ dinv,         // [N][3] (this layer)
        int N){
    int w = threadIdx.x >> 6, lane = threadIdx.x & 63;
    int t = blockIdx.x * 4 + w;
    if (t >= N) return;
    float ax0 = 0.f, ay0 = 0.f, ax1 = 0.f, ay1 = 0.f, ax2 = 0.f, ay2 = 0.f;
    int beg = rs[t], end = rs[t + 1];
    int i = beg;
    for (; i + 8 <= end; i += 8){
        uint2 m[8];
        #pragma unroll
        for (int u = 0; u < 8; ++u) m[u] = nv[i + u];
        float2 f[8];
        #pragma unroll
        for (int u = 0; u < 8; ++u){
            const __hip_bfloat162* p =
                (const __hip_bfloat162*)(xg + (size_t)(m[u].x & 0xFFFFu) * 128);
            f[u] = __bfloat1622float2(p[lane]);
        }
        #pragma unroll
        for (int u = 0; u < 8; ++u){
            float n0 = bf16hi_to_f32(m[u].x & 0xFFFF0000u);
            float n1 = bf16hi_to_f32(m[u].y << 16);
            float n2 = bf16hi_to_f32(m[u].y & 0xFFFF0000u);
            ax0 += n0 * f[u].x; ay0 += n0 * f[u].y;
            ax1 += n1 * f[u].x; ay1 += n1 * f[u].y;
            ax2 += n2 * f[u].x; ay2 += n2 * f[u].y;
        }
    }
    for (; i < end; ++i){
        uint2 m = nv[i];
        const __hip_bfloat162* p =
            (const __hip_bfloat162*)(xg + (size_t)(m.x & 0xFFFFu) * 128);
        float2 fv = __bfloat1622float2(p[lane]);
        float n0 = bf16hi_to_f32(m.x & 0xFFFF0000u);
        float n1 = bf16hi_to_f32(m.y << 16);
        float n2 = bf16hi_to_f32(m.y & 0xFFFF0000u);
        ax0 += n0 * fv.x; ay0 += n0 * fv.y;
        ax1 += n1 * fv.x; ay1 += n1 * fv.y;
        ax2 += n2 * fv.x; ay2 += n2 * fv.y;
    }
    float dt0 = dinv[3 * t], dt1 = dinv[3 * t + 1], dt2 = dinv[3 * t + 2];
    __hip_bfloat162* yo = (__hip_bfloat162*)(Yg + (size_t)t * 384) + lane;
    float2 r0 = {dt0 * ax0, dt0 * ay0};
    float2 r1 = {dt1 * ax1, dt1 * ay1};
    float2 r2 = {dt2 * ax2, dt2 * ay2};
    yo[0]   = __float22bfloat162_rn(r0);
    yo[64]  = __float22bfloat162_rn(r1);
    yo[128] = __float22bfloat162_rn(r2);
}

// ---------------- GEMM: out = [xg|Yg][M,512] @ B[512,128] + bias; opt fused LN+ReLU
// BM=64: grid 391->782 blocks, LDS 64->48KB (3 blocks/CU vs 2) — more resident
// blocks to hide per-kt staging latency across barriers. BT (131KB) is L2-resident
// so the doubled B re-staging is ~free.
__global__ __launch_bounds__(256) void k_gemm(
        const __hip_bfloat16* __restrict__ Yg,  // [M,384] bf16
        const __hip_bfloat16* __restrict__ BT,  // [128,512] bf16 ([j][k])
        const float* __restrict__ bias,         // [128] fp32
        float* __restrict__ outbuf,             // [M,128] (doLN==0)
        int M, int doLN,
        const float* __restrict__ g, const float* __restrict__ b,
        __hip_bfloat16* __restrict__ xg){       // [M,128]: A kt=0 source; LN target
    __shared__ __hip_bfloat16 As[64 * 128];     // 16KB
    __shared__ __hip_bfloat16 Bs[128 * 128];    // 32KB
    const int tid = threadIdx.x;
    const int row0 = blockIdx.x * 64;
    const int w = tid >> 6, lane = tid & 63;
    const int wm = (w & 1) * 32, wn = (w >> 1) * 64;
    const int lm = lane & 15, lq = lane >> 4;

    f32x4 acc[2][4];
    #pragma unroll
    for (int mt = 0; mt < 2; ++mt)
        #pragma unroll
        for (int nt = 0; nt < 4; ++nt)
            acc[mt][nt] = {0.f, 0.f, 0.f, 0.f};

    for (int kt = 0; kt < 4; ++kt){
        #pragma unroll
        for (int it = 0; it < 4; ++it){
            int v = it * 256 + tid;
            int r = v >> 4, c = v & 15;
            int soff = r * 128 + ((c ^ (r & 15)) << 3);
            int4 av = {0, 0, 0, 0};
            if (row0 + r < M){
                if (kt == 0)
                    av = *(const int4*)(xg + (size_t)(row0 + r) * 128 + (c << 3));
                else
                    av = *(const int4*)(Yg + (size_t)(row0 + r) * 384
                                        + (kt - 1) * 128 + (c << 3));
            }
            *(int4*)(&As[soff]) = av;
        }
        #pragma unroll
        for (int it = 0; it < 8; ++it){
            int v = it * 256 + tid;
            int r = v >> 4, c = v & 15;
            int soff = r * 128 + ((c ^ (r & 15)) << 3);
            int4 bv = *(const int4*)(BT + (size_t)r * 512 + kt * 128 + (c << 3));
            *(int4*)(&Bs[soff]) = bv;
        }
        __syncthreads();

        #pragma unroll
        for (int kk = 0; kk < 4; ++kk){
            int kc = kk * 4 + lq;
            bf16x8 a[2], b2[4];
            #pragma unroll
            for (int mt = 0; mt < 2; ++mt){
                int r = wm + mt * 16 + lm;
                a[mt] = *(const bf16x8*)(&As[r * 128 + ((kc ^ (r & 15)) << 3)]);
            }
            #pragma unroll
            for (int nt = 0; nt < 4; ++nt){
                int r = wn + nt * 16 + lm;
                b2[nt] = *(const bf16x8*)(&Bs[r * 128 + ((kc ^ (r & 15)) << 3)]);
            }
            #pragma unroll
            for (int mt = 0; mt < 2; ++mt)
                #pragma unroll
                for (int nt = 0; nt < 4; ++nt)
                    acc[mt][nt] = __builtin_amdgcn_mfma_f32_16x16x32_bf16(
                        a[mt], b2[nt], acc[mt][nt], 0, 0, 0);
        }
        __syncthreads();
    }

    if (!doLN){
        #pragma unroll
        for (int mt = 0; mt < 2; ++mt){
            #pragma unroll
            for (int nt = 0; nt < 4; ++nt){
                int col = wn + nt * 16 + lm;
                #pragma unroll
                for (int r = 0; r < 4; ++r){
                    int row = row0 + wm + mt * 16 + lq * 4 + r;
                    if (row < M)
                        outbuf[(size_t)row * 128 + col] = acc[mt][nt][r] + bias[col];
                }
            }
        }
    } else {
        // fused LN+ReLU epilogue. As: S1[64][32]+S2[64][32] (16KB exact); Bs: mu/sc.
        float* S1 = (float*)As;          // [64][32] sum partials
        float* S2 = S1 + 2048;           // [64][32] sumsq partials
        float* MS = (float*)Bs;          // mu[64], sc[64]
        const int half = wn >> 6;        // 0 or 1
        const int slot = half * 16 + lm;
        float bv[4];
        #pragma unroll
        for (int nt = 0; nt < 4; ++nt) bv[nt] = bias[wn + nt * 16 + lm];
        #pragma unroll
        for (int mt = 0; mt < 2; ++mt){
            #pragma unroll
            for (int r = 0; r < 4; ++r){
                int rl = wm + mt * 16 + lq * 4 + r;
                float ps = 0.f, pq = 0.f;
                #pragma unroll
                for (int nt = 0; nt < 4; ++nt){
                    float v = acc[mt][nt][r] + bv[nt];
                    ps += v; pq += v * v;
                }
                S1[rl * 32 + slot] = ps;
                S2[rl * 32 + slot] = pq;
            }
        }
        __syncthreads();
        if (tid < 64){
            float s = 0.f, sq = 0.f;
            #pragma unroll
            for (int j = 0; j < 32; ++j){
                s  += S1[tid * 32 + j];
                sq += S2[tid * 32 + j];
            }
            float mu = s * (1.0f / 128.0f);
            float var = sq * (1.0f / 128.0f) - mu * mu;
            MS[tid] = mu;
            MS[64 + tid] = rsqrtf(var + 1e-5f);
        }
        __syncthreads();
        float gv[4], bbv[4];
        #pragma unroll
        for (int nt = 0; nt < 4; ++nt){
            int col = wn + nt * 16 + lm;
            gv[nt] = g[col]; bbv[nt] = b[col];
        }
        #pragma unroll
        for (int mt = 0; mt < 2; ++mt){
            #pragma unroll
            for (int r = 0; r < 4; ++r){
                int rl = wm + mt * 16 + lq * 4 + r;
                int row = row0 + rl;
                if (row < M){
                    float mu = MS[rl], sc = MS[64 + rl];
                    #pragma unroll
                    for (int nt = 0; nt < 4; ++nt){
                        int col = wn + nt * 16 + lm;
                        float v = acc[mt][nt][r] + bv[nt];
                        float y = fmaxf((v - mu) * sc * gv[nt] + bbv[nt], 0.0f);
                        xg[(size_t)row * 128 + col] = __float2bfloat16(y);
                    }
                }
            }
        }
    }
}

extern "C" void kernel_launch(void* const* d_in, const int* in_sizes, int n_in,
                              void* d_out, int out_size, void* d_ws, size_t ws_size,
                              hipStream_t stream) {
    const float* x     = (const float*)d_in[0];
    const int*   ei    = (const int*)d_in[1];
    const float* asp   = (const float*)d_in[2];
    const float* actx  = (const float*)d_in[3];
    const float* alat  = (const float*)d_in[4];
    const float* wsp   = (const float*)d_in[5];
    const float* wctx  = (const float*)d_in[6];
    const float* wlat  = (const float*)d_in[7];
    const float* W3    = (const float*)d_in[8];
    const float* Wself = (const float*)d_in[9];
    const float* bias  = (const float*)d_in[10];
    const float* dpow  = (const float*)d_in[11];
    const float* lng   = (const float*)d_in[12];
    const float* lnb   = (const float*)d_in[13];

    const int N = in_sizes[0] / 128;
    const int E = in_sizes[1] / 2;
    const int L = in_sizes[8] / (3 * 128 * 128);
    const int NB = cdiv(N, BK);
    const int* src = ei;
    const int* tgt = ei + E;

    // workspace carve (256B-aligned) — layout identical to round 6 (passed)
    char* p = (char*)d_ws;
    auto alloc = [&](size_t bytes) -> void* {
        void* r = (void*)p;
        p += (bytes + 255) & ~(size_t)255;
        return r;
    };
    int*   rs       = (int*)  alloc((size_t)(N + 1) * 4);
    int*   gcnt     = (int*)  alloc(1024 * 4);
    int*   bbase    = (int*)  alloc(1025 * 4);
    int*   gcur     = (int*)  alloc(1024 * 4);
    uint2* effo     = (uint2*)alloc((size_t)E * 8);
    size_t nv_bytes = (size_t)L * E * 8, bn_bytes = (size_t)E * 16;
    uint2* nv       = (uint2*)alloc(nv_bytes > bn_bytes ? nv_bytes : bn_bytes);
    float* dinv_all = (float*)alloc((size_t)L * N * 3 * 4);   // [L][N][3]
    __hip_bfloat16* xg = (__hip_bfloat16*)alloc((size_t)N * 128 * 2);  // [N][128]
    __hip_bfloat16* Yg = (__hip_bfloat16*)alloc((size_t)N * 384 * 2);  // [N][384]
    __hip_bfloat16* BT = (__hip_bfloat16*)alloc((size_t)L * 128 * 512 * 2);
    // binned (E*16B) aliased onto nv: dead before k_prep writes nv (round-6 proven)
    uint4* binned = (uint4*)nv;

    // ---- prep: bucketed counting-sort CSR build ----
    hipMemsetAsync(gcnt, 0, 1024 * 4, stream);
    k_bcnt0 <<<cdiv(E, 4096), 256, 0, stream>>>(tgt, gcnt, E, NB);
    k_bscan <<<1, 256, 0, stream>>>(gcnt, bbase, gcur, rs, N, E);
    k_bin   <<<cdiv(E, 4096), 256, 0, stream>>>(src, tgt, asp, actx, alat, wsp, wctx, wlat,
                                                gcur, binned, E, NB);
    k_bucket<<<NB, 256, 0, stream>>>(binned, bbase, dpow, effo, rs, dinv_all, N, L);
    {
        int total = L * E + ((N * 128) >> 2) + L * 65536;
        k_prep<<<cdiv(total, 256), 256, 0, stream>>>(effo, dinv_all, nv, x, xg,
                                                     Wself, W3, BT, N, E, L);
    }

    // ---- layers ----
    for (int l = 0; l < L; ++l){
        int doLN = (l < L - 1) ? 1 : 0;
        const float* dinv_l = dinv_all + (size_t)l * N * 3;
        k_msg <<<cdiv(N, 4), 256, 0, stream>>>(xg, Yg, nv + (size_t)l * E, rs, dinv_l, N);
        k_gemm<<<cdiv(N, 64), 256, 0, stream>>>(Yg, BT + (size_t)l * 65536,
                                                bias + l * 128, (float*)d_out, N,
                                                doLN, lng, lnb, xg);
    }
}